// Round 4
// baseline (363.073 us; speedup 1.0000x reference)
//
#include <hip/hip_runtime.h>
#include <math.h>

#define B_ 4
#define N_ 50000
#define E_ 800000
#define D_ 64
#define M_ (B_*N_)   // 200000 rows for the linear

typedef _Float16 h4 __attribute__((ext_vector_type(4)));
typedef _Float16 h8 __attribute__((ext_vector_type(8)));
typedef float    f4 __attribute__((ext_vector_type(4)));

// ---------- CSR build ----------
__global__ __launch_bounds__(256) void k_count(const int4* __restrict__ col4, int* __restrict__ cnt) {
  int e = blockIdx.x * 256 + threadIdx.x;
  if (e < E_ / 4) {
    int4 c = col4[e];
    atomicAdd(&cnt[c.x], 1);
    atomicAdd(&cnt[c.y], 1);
    atomicAdd(&cnt[c.z], 1);
    atomicAdd(&cnt[c.w], 1);
  }
}

// fused scan: dis + padded-degree block scan + atomic global base + pad fill.
// Buckets padded to multiple of 16 so k_agg's inner loop is branchless; pad
// entries point at the zeroed row N_ of each batch plane (L1-hot -> free).
// off[] is only a start pointer (block bases in arbitrary order is fine:
// k_agg uses off[i] + degp, never off[i+1]).
__global__ __launch_bounds__(1024) void k_scan(const int* __restrict__ cnt,
                                               float* __restrict__ dis,
                                               int* __restrict__ off, int* __restrict__ cur,
                                               int* __restrict__ em, int* __restrict__ gbase,
                                               _Float16* __restrict__ xw) {
  __shared__ int sd[1024];
  __shared__ int base_s;
  int i = blockIdx.x * 1024 + threadIdx.x;
  int v = (i < N_) ? cnt[i] : 0;
  int degp = (v + 15) & ~15;
  if (i < N_) dis[i] = 1.0f / sqrtf((float)(v + 1));  // +1 self-loop
  sd[threadIdx.x] = degp;
  __syncthreads();
  for (int s = 1; s < 1024; s <<= 1) {               // inclusive scan of degp
    int t = (threadIdx.x >= s) ? sd[threadIdx.x - s] : 0;
    __syncthreads();
    sd[threadIdx.x] += t;
    __syncthreads();
  }
  if (threadIdx.x == 1023) base_s = atomicAdd(gbase, sd[1023]);
  __syncthreads();
  int o = base_s + sd[threadIdx.x] - degp;
  if (i < N_) {
    off[i] = o;
    cur[i] = 0;
    for (int k = v; k < degp; k++) em[o + k] = N_ * 128;  // pads -> zero row
  }
  if (blockIdx.x == 0 && threadIdx.x < 32) {
    // zero the pad row (row N_) of each of the B_ batch planes (4 x 128B)
    int pl = threadIdx.x >> 3, q = threadIdx.x & 7;
    h8 z = {};
    *(h8*)((char*)xw + (size_t)pl * (N_ + 1) * 128 + (size_t)N_ * 128 + q * 16) = z;
  }
}

// fill packed edge metadata: em[p] = src-row byte offset within a batch plane
// (row piece = 64 fp16 = 128 B). Weight dis[r]*dis[c] is folded into xw rows
// (dis[r], in k_linear) and the uniform dis[c] multiply in k_agg -> 4 B/edge.
__global__ __launch_bounds__(256) void k_fill(const int* __restrict__ row, const int* __restrict__ col,
                                              const int* __restrict__ off, int* __restrict__ cur,
                                              int* __restrict__ em) {
  int e = blockIdx.x * 256 + threadIdx.x;
  if (e < E_) {
    int c = col[e], r = row[e];
    int p = off[c] + atomicAdd(&cur[c], 1);
    em[p] = r << 7;                                  // r*128 = byte offset of row r
  }
}

// ---------- W fragment pre-pack: Wf[khalf][t][lane] = 8 contiguous-k fp16 of W[k][t*16+m] ----------
// B-frag layout for mfma_f32_16x16x32_f16: lane l holds B[k=(l>>4)*8+j][n=l&15], j=0..7.
__global__ __launch_bounds__(256) void k_wfrag(const float* __restrict__ W1, const float* __restrict__ W2,
                                               h8* __restrict__ Wf1, h8* __restrict__ Wf2) {
  int t0 = threadIdx.x;
  for (int w = 0; w < 2; w++) {
    const float* W = w ? W2 : W1;
    h8* Wf = w ? Wf2 : Wf1;
    for (int p = 0; p < 2; p++) {
      int fid = p * 256 + t0;          // 0..511
      int khalf = fid >> 8;
      int rem = fid & 255;
      int tt = rem >> 6;
      int lane = rem & 63;
      int kq = lane >> 4, m = lane & 15;
      h8 v;
#pragma unroll
      for (int j = 0; j < 8; j++) {
        int k = khalf * 32 + kq * 8 + j;
        v[j] = (_Float16)W[k * 64 + tt * 16 + m];
      }
      Wf[fid] = v;
    }
  }
}

// ---------- Linear: Y = (X @ W) * dis[n] -> fp16 padded batch planes ----------
// One wave per 16 rows. A-frag: lane holds X[r0+(l&15)][(l>>4)*8 + j].
// 8x mfma_f32_16x16x32_f16. D: col=lane&15, row=(lane>>4)*4+reg.
// dis[n] is folded here BEFORE the single fp16 rounding (same error profile as
// unscaled-fp16 * exact-w). Output row b*(N_+1)+n (planes padded by 1 zero row).
template<int IN_F16>
__global__ __launch_bounds__(256) void k_linear(const void* __restrict__ Xv,
                                                const h8* __restrict__ Wf,
                                                const float* __restrict__ dis,
                                                _Float16* __restrict__ Y) {
  int wv = blockIdx.x * 4 + (threadIdx.x >> 6);
  int lane = threadIdx.x & 63;
  int m = lane & 15, kq = lane >> 4;
  size_t r0 = (size_t)wv * 16;
  h8 a0, a1;
  if constexpr (IN_F16) {
    const _Float16* xr = (const _Float16*)Xv + (r0 + m) * 64 + kq * 8;
    a0 = *(const h8*)(xr);
    a1 = *(const h8*)(xr + 32);
  } else {
    const float* xr = (const float*)Xv + (r0 + m) * 64 + kq * 8;
    f4 f0 = *(const f4*)(xr);
    f4 f1 = *(const f4*)(xr + 4);
    f4 f2 = *(const f4*)(xr + 32);
    f4 f3 = *(const f4*)(xr + 36);
#pragma unroll
    for (int j = 0; j < 4; j++) {
      a0[j] = (_Float16)f0[j]; a0[j + 4] = (_Float16)f1[j];
      a1[j] = (_Float16)f2[j]; a1[j + 4] = (_Float16)f3[j];
    }
  }
  f4 acc[4];
#pragma unroll
  for (int t = 0; t < 4; t++) {
    h8 b0 = Wf[t * 64 + lane];         // khalf 0
    h8 b1 = Wf[256 + t * 64 + lane];   // khalf 1
    f4 c = {0.f, 0.f, 0.f, 0.f};
    c = __builtin_amdgcn_mfma_f32_16x16x32_f16(a0, b0, c, 0, 0, 0);
    c = __builtin_amdgcn_mfma_f32_16x16x32_f16(a1, b1, c, 0, 0, 0);
    acc[t] = c;
  }
  int b  = (int)(r0 / N_);             // wave never straddles b (50000 % 16 == 0)
  int n0 = (int)(r0 - (size_t)b * N_);
  float dv[4];
#pragma unroll
  for (int rr = 0; rr < 4; rr++) dv[rr] = dis[n0 + kq * 4 + rr];
  size_t ybase = ((size_t)b * (N_ + 1) + n0) * 64;
#pragma unroll
  for (int t = 0; t < 4; t++) {
#pragma unroll
    for (int rr = 0; rr < 4; rr++) {
      Y[ybase + (size_t)(kq * 4 + rr) * 64 + t * 16 + m] = (_Float16)(acc[t][rr] * dv[rr]);
    }
  }
}

// ---------- Aggregate (batch-split, scalarized, pad-16) ----------
// One wave per (node, batch); lane owns dim d = lane (2 B slot). Per edge the
// gather is 128 B (64 lanes x ushort) from the 6.4 MB batch plane -> working
// set per batch phase is L2-scale (was 25.6 MB). Edge stream is 4 B scalar
// offsets, buckets padded to x16 -> branchless 16-deep inner loop, all edge
// metadata on the scalar pipe. Final: out = tanh(dis_c * (self' + sum) + bias).
template<int OUT_F16>
__global__ __launch_bounds__(512) void k_agg(const _Float16* __restrict__ xw,
                                             const int* __restrict__ off,
                                             const int* __restrict__ cnt,
                                             const int* __restrict__ em,
                                             const float* __restrict__ bias,
                                             void* __restrict__ outv) {
  int wid = __builtin_amdgcn_readfirstlane(blockIdx.x * 8 + (threadIdx.x >> 6));
  int lane = threadIdx.x & 63;
  int b    = (int)((unsigned)wid / N_);      // b-major: batch phases serialize
  int node = wid - b * N_;
  const char* plane = (const char*)xw + (size_t)b * (N_ + 1) * 128 + (size_t)(lane * 2);
  int s0   = __builtin_amdgcn_readfirstlane(off[node]);
  int deg  = __builtin_amdgcn_readfirstlane(cnt[node]);
  int degp = (deg + 15) & ~15;
  float dc = 1.0f / sqrtf((float)(deg + 1));   // dis[node]
  float acc = (float)*(const _Float16*)(plane + (size_t)node * 128);  // self (dis[src]-scaled)
  for (int j = s0; j < s0 + degp; j += 16) {
    int o[16];
#pragma unroll
    for (int k = 0; k < 16; k++) o[k] = em[j + k];           // scalar s_loads
    _Float16 v[16];
#pragma unroll
    for (int k = 0; k < 16; k++) v[k] = *(const _Float16*)(plane + (unsigned)o[k]);
#pragma unroll
    for (int k = 0; k < 16; k++) acc += (float)v[k];
  }
  float r = tanhf(acc * dc + bias[lane]);
  if constexpr (OUT_F16) {
    ((_Float16*)outv)[((size_t)b * N_ + node) * 64 + lane] = (_Float16)r;
  } else {
    ((float*)outv)[((size_t)b * N_ + node) * 64 + lane] = r;
  }
}

extern "C" void kernel_launch(void* const* d_in, const int* in_sizes, int n_in,
                              void* d_out, int out_size, void* d_ws, size_t ws_size,
                              hipStream_t stream) {
  const float* h  = (const float*)d_in[1];
  const int*   ei = (const int*)d_in[2];
  const float* W1 = (const float*)d_in[3];
  const float* b1 = (const float*)d_in[4];
  const float* W2 = (const float*)d_in[5];
  const float* b2 = (const float*)d_in[6];
  float* out = (float*)d_out;
  const int* row = ei;        // edge_index[0] = sources
  const int* col = ei + E_;   // edge_index[1] = targets

  // workspace layout (~33 MB)
  char* p = (char*)d_ws;
  _Float16* xw = (_Float16*)p; p += (size_t)B_ * (N_ + 1) * 64 * sizeof(_Float16); // 25.6 MB, 4 padded planes
  int*  em  = (int*)p;    p += (size_t)(E_ + 15 * N_ + 64) * sizeof(int);          // 6.2 MB (padded CSR)
  int*  cnt = (int*)p;    p += (size_t)N_ * sizeof(int);
  int*  gbase = (int*)p;  p += 4 * sizeof(int);        // directly after cnt: one memset covers both
  int*  off = (int*)p;    p += (size_t)N_ * sizeof(int);
  int*  cur = (int*)p;    p += (size_t)N_ * sizeof(int);
  float* dis = (float*)p; p += (size_t)N_ * sizeof(float);
  h8*   Wf1 = (h8*)p;     p += 512 * sizeof(h8);                                   // 8 KB
  h8*   Wf2 = (h8*)p;     p += 512 * sizeof(h8);                                   // 8 KB
  // layer-1 output h1 is fp16 [M][64], staged in d_out's first 25.6 MB
  // (consumed by layer-2 k_linear before the final f32 write overwrites d_out)
  _Float16* h1 = (_Float16*)d_out;

  hipMemsetAsync(cnt, 0, (N_ + 1) * sizeof(int), stream);   // cnt + gbase

  k_count<<<(E_ / 4 + 255) / 256, 256, 0, stream>>>((const int4*)col, cnt);
  int nscan = (N_ + 1023) / 1024;  // 49
  k_scan<<<nscan, 1024, 0, stream>>>(cnt, dis, off, cur, em, gbase, xw);
  k_fill<<<(E_ + 255) / 256, 256, 0, stream>>>(row, col, off, cur, em);
  k_wfrag<<<1, 256, 0, stream>>>(W1, W2, Wf1, Wf2);

  // layer 1
  k_linear<0><<<M_ / 64, 256, 0, stream>>>(h, Wf1, dis, xw);
  k_agg<1><<<(B_ * N_) / 8, 512, 0, stream>>>(xw, off, cnt, em, b1, h1);
  // layer 2
  k_linear<1><<<M_ / 64, 256, 0, stream>>>(h1, Wf2, dis, xw);
  k_agg<0><<<(B_ * N_) / 8, 512, 0, stream>>>(xw, off, cnt, em, b2, out);
}